// Round 3
// baseline (739.280 us; speedup 1.0000x reference)
//
#include <hip/hip_runtime.h>
#include <hip/hip_bf16.h>
#include <stdint.h>

#define NOUT 11008
#define KIN  4096
#define MTOK 4096
#define PLD  (NOUT/2)       // 5504 int32 elements per k-row (1 packed byte / int32)
#define BM 128
#define BN 128
#define BK 64
#define NSTEP (KIN/BK)      // 64
#define NTN (NOUT/BN)       // 86

typedef short bf16x8 __attribute__((ext_vector_type(8)));
typedef float f32x4  __attribute__((ext_vector_type(4)));

__device__ __forceinline__ int swzb(int r){ return (((r & 7) ^ ((r >> 3) & 7)) << 4); }

__device__ __forceinline__ uint32_t bfpack(float lo, float hi){
    __hip_bfloat16 a = __float2bfloat16(lo);
    __hip_bfloat16 b = __float2bfloat16(hi);
    uint16_t ua, ub;
    __builtin_memcpy(&ua, &a, 2);
    __builtin_memcpy(&ub, &b, 2);
    return (uint32_t)ua | ((uint32_t)ub << 16);
}

__global__ __launch_bounds__(256, 2)
void qlin_gemm(const float* __restrict__ x, const int32_t* __restrict__ pw,
               const float* __restrict__ sc, const float* __restrict__ bias,
               float* __restrict__ y)
{
    __shared__ __align__(16) uint8_t ldsA[2][BM * 128];   // [row m][64 k * 2B], swizzled
    __shared__ __align__(16) uint8_t ldsB[2][BN * 128];   // [row o][64 k * 2B], swizzled

    const int tid  = threadIdx.x;
    const int lane = tid & 63;
    const int wid  = tid >> 6;
    const int wr = wid >> 1, wc = wid & 1;   // 2x2 wave grid, 64x64 per wave

    const int nt = blockIdx.x % NTN;
    const int mt = blockIdx.x / NTN;
    const int m0 = mt * BM, n0 = nt * BN;

    // ---- fragment read offsets (byte, within swizzled LDS row) ----
    const int cl = lane & 15;
    const int kl = (lane >> 4) << 4;   // k-lane group byte offset (8 bf16 = 16B)

    int aOff[4], bOff[4];
#pragma unroll
    for (int i = 0; i < 4; ++i) {
        int m = wr * 64 + i * 16 + cl;
        aOff[i] = m * 128 + (kl ^ swzb(m));
        int o = wc * 64 + i * 16 + cl;
        bOff[i] = o * 128 + (kl ^ swzb(o));
    }

    // ---- A staging mapping: 16 threads/row-slice, rows ar+16*it ----
    const int ac = tid & 15;           // k chunk: 4 floats at k = ac*4
    const int ar = tid >> 4;
    const float* xbase = x + (size_t)(m0 + ar) * KIN + ac * 4;
    int aW[8];
#pragma unroll
    for (int it = 0; it < 8; ++it) {
        int m = ar + 16 * it;
        aW[it] = m * 128 + ((ac * 8) ^ swzb(m));
    }

    // ---- B staging: og = 8 outs at o=og*8 (= 4 int32), bkg -> k = bkg*4+i ----
    const int og  = tid & 15;
    const int bkg = tid >> 4;
    const int32_t* pwbase = pw + (size_t)bkg * 4 * PLD + ((n0 + og * 8) >> 1);
    const float*   scbase = sc + n0 + og * 8;
    int bW[8];
#pragma unroll
    for (int j = 0; j < 8; ++j) {
        int o = og * 8 + j;
        bW[j] = o * 128 + ((bkg * 8) ^ swzb(o));
    }

    f32x4 acc[4][4];
    const f32x4 zero4 = {0.f, 0.f, 0.f, 0.f};
#pragma unroll
    for (int i = 0; i < 4; ++i)
#pragma unroll
        for (int j = 0; j < 4; ++j)
            acc[i][j] = zero4;

    // prefetch registers
    float4 aR[8];
    int4 bR4[4];            // 4 k's x (4 int32 = 4 packed bytes = 8 out channels)
    float sv[8];

    auto loadTile = [&](int t) {
        const float* xp = xbase + t * BK;
#pragma unroll
        for (int it = 0; it < 8; ++it)
            aR[it] = *reinterpret_cast<const float4*>(xp + (size_t)(16 * it) * KIN);
        const int32_t* bp = pwbase + (size_t)t * BK * PLD;
#pragma unroll
        for (int i = 0; i < 4; ++i)
            bR4[i] = *reinterpret_cast<const int4*>(bp + (size_t)i * PLD);
        const float* sp = scbase + (size_t)(t >> 1) * NOUT;  // k-block = t/2 (BK=64, block=128)
        float4 s0 = *reinterpret_cast<const float4*>(sp);
        float4 s1 = *reinterpret_cast<const float4*>(sp + 4);
        sv[0]=s0.x; sv[1]=s0.y; sv[2]=s0.z; sv[3]=s0.w;
        sv[4]=s1.x; sv[5]=s1.y; sv[6]=s1.z; sv[7]=s1.w;
    };

    auto storeTile = [&](int buf) {
        uint8_t* La = ldsA[buf];
#pragma unroll
        for (int it = 0; it < 8; ++it) {
            uint64_t v = (uint64_t)bfpack(aR[it].x, aR[it].y)
                       | ((uint64_t)bfpack(aR[it].z, aR[it].w) << 32);
            *reinterpret_cast<uint64_t*>(La + aW[it]) = v;
        }
        uint8_t* Lb = ldsB[buf];
        float no8[8];
#pragma unroll
        for (int j = 0; j < 8; ++j) no8[j] = -8.f * sv[j];
        float dq[4][8];
#pragma unroll
        for (int i = 0; i < 4; ++i) {
            const int bb[4] = {bR4[i].x, bR4[i].y, bR4[i].z, bR4[i].w};
#pragma unroll
            for (int t4 = 0; t4 < 4; ++t4) {
                const uint32_t b = (uint32_t)bb[t4] & 0xFFu;   // the packed byte
                dq[i][2*t4]   = fmaf((float)(b & 15u), sv[2*t4],   no8[2*t4]);
                dq[i][2*t4+1] = fmaf((float)(b >> 4),  sv[2*t4+1], no8[2*t4+1]);
            }
        }
#pragma unroll
        for (int j = 0; j < 8; ++j) {
            uint64_t v = (uint64_t)bfpack(dq[0][j], dq[1][j])
                       | ((uint64_t)bfpack(dq[2][j], dq[3][j]) << 32);
            *reinterpret_cast<uint64_t*>(Lb + bW[j]) = v;
        }
    };

    auto compute = [&](int buf) {
        const uint8_t* La = ldsA[buf];
        const uint8_t* Lb = ldsB[buf];
#pragma unroll
        for (int kk = 0; kk < 2; ++kk) {
            const int kx = kk * 64;   // byte offset of k-half (32 elems * 2B)
            bf16x8 af[4], bfr[4];
#pragma unroll
            for (int i = 0; i < 4; ++i)
                af[i] = *reinterpret_cast<const bf16x8*>(La + (aOff[i] ^ kx));
#pragma unroll
            for (int j = 0; j < 4; ++j)
                bfr[j] = *reinterpret_cast<const bf16x8*>(Lb + (bOff[j] ^ kx));
#pragma unroll
            for (int i = 0; i < 4; ++i)
#pragma unroll
                for (int j = 0; j < 4; ++j)
                    acc[i][j] = __builtin_amdgcn_mfma_f32_16x16x32_bf16(af[i], bfr[j], acc[i][j], 0, 0, 0);
        }
    };

    loadTile(0);
    storeTile(0);
    __syncthreads();

    int cur = 0;
#pragma unroll 1
    for (int t = 0; t < NSTEP; ++t) {
        if (t + 1 < NSTEP) loadTile(t + 1);   // issue next-tile global loads early
        compute(cur);
        if (t + 1 < NSTEP) storeTile(cur ^ 1);
        __syncthreads();
        cur ^= 1;
    }

    // ---- epilogue: acc + bias -> y ----
    const int rg = (lane >> 4) * 4;
    float bv[4];
#pragma unroll
    for (int j = 0; j < 4; ++j) bv[j] = bias[n0 + wc * 64 + j * 16 + cl];
#pragma unroll
    for (int i = 0; i < 4; ++i) {
        const int mrow = m0 + wr * 64 + i * 16 + rg;
#pragma unroll
        for (int r = 0; r < 4; ++r) {
            float* yp = y + (size_t)(mrow + r) * NOUT + n0 + wc * 64 + cl;
#pragma unroll
            for (int j = 0; j < 4; ++j)
                yp[j * 16] = acc[i][j][r] + bv[j];
        }
    }
}

extern "C" void kernel_launch(void* const* d_in, const int* in_sizes, int n_in,
                              void* d_out, int out_size, void* d_ws, size_t ws_size,
                              hipStream_t stream)
{
    const float*   xin  = (const float*)d_in[0];
    const int32_t* pw   = (const int32_t*)d_in[1];   // harness pushes int8 as int32
    const float*   scal = (const float*)d_in[2];
    const float*   bias = (const float*)d_in[3];
    float* y = (float*)d_out;

    dim3 grid((MTOK / BM) * NTN);   // 32 * 86 = 2752
    qlin_gemm<<<grid, 256, 0, stream>>>(xin, pw, scal, bias, y);
}

// Round 4
// 515.681 us; speedup vs baseline: 1.4336x; 1.4336x over previous
//
#include <hip/hip_runtime.h>
#include <hip/hip_bf16.h>
#include <stdint.h>

#define NOUT 11008
#define KIN  4096
#define MTOK 4096
#define PLD  5504            // int32 elements per k-row of pw
#define BM 256
#define BN 128
#define BK 32
#define NSTEP (KIN/BK)       // 128
#define NTN (NOUT/BN)        // 86
#define NTM (MTOK/BM)        // 16
#define ACHUNK 16384         // bytes per (mt,t) A chunk: 256 rows * 64B
#define WSA_BYTES ((size_t)NTM * NSTEP * ACHUNK)        // 32 MB
#define WSB_OFF   WSA_BYTES

typedef short bf16x8 __attribute__((ext_vector_type(8)));
typedef float f32x4  __attribute__((ext_vector_type(4)));

typedef __attribute__((address_space(3))) uint8_t lds_u8_t;
typedef __attribute__((address_space(1))) const uint8_t glb_u8_t;

__device__ __forceinline__ uint32_t bfpack(float lo, float hi){
    __hip_bfloat16 a = __float2bfloat16(lo);
    __hip_bfloat16 b = __float2bfloat16(hi);
    uint16_t ua, ub;
    __builtin_memcpy(&ua, &a, 2);
    __builtin_memcpy(&ub, &b, 2);
    return (uint32_t)ua | ((uint32_t)ub << 16);
}

// A-LDS swizzle: rows are 64B (32k * 2B); slot16(m,k8) spreads 16 rows x 4 slots
// over the 8 bank-slots 2x each (2-way = free, m136).
__device__ __forceinline__ int swzA(int m){ return ((m >> 1) & 3) << 4; }

// ---------------- pre-pass A: x fp32 -> bf16, tiled+swizzled into wsA ----------------
__global__ __launch_bounds__(256)
void prepA(const float* __restrict__ x, uint8_t* __restrict__ wsA)
{
    int gid = blockIdx.x * 256 + threadIdx.x;      // 4096 * 1024
    int m  = gid >> 10;
    int k  = (gid & 1023) << 2;
    float4 v = *reinterpret_cast<const float4*>(x + (size_t)m * KIN + k);
    uint32_t lo = bfpack(v.x, v.y), hi = bfpack(v.z, v.w);
    int mt = m >> 8, ml = m & 255, t = k >> 5, kl = k & 31;
    size_t dst = (size_t)(mt * NSTEP + t) * ACHUNK + ml * 64 + ((kl * 2) ^ swzA(ml));
    *reinterpret_cast<uint2*>(wsA + dst) = make_uint2(lo, hi);
}

// ---------------- pre-pass B: int32-inflated nibble-pairs -> compact bytes, k-transposed ----------------
// wsB layout: [koct 0..511][np 0..5503] of 8B: bytes for k = koct*8+0..7 at column np.
__global__ __launch_bounds__(128)
void prepB(const int32_t* __restrict__ pw, uint8_t* __restrict__ wsB)
{
    int np   = blockIdx.x * 128 + threadIdx.x;     // 43*128 = 5504
    int koct = blockIdx.y;                         // 0..511
    const int32_t* p = pw + (size_t)koct * 8 * PLD + np;
    uint32_t b[8];
#pragma unroll
    for (int i = 0; i < 8; ++i) b[i] = (uint32_t)p[(size_t)i * PLD] & 0xFFu;
    uint32_t lo = b[0] | (b[1] << 8) | (b[2] << 16) | (b[3] << 24);
    uint32_t hi = b[4] | (b[5] << 8) | (b[6] << 16) | (b[7] << 24);
    *reinterpret_cast<uint2*>(wsB + ((size_t)koct * PLD + np) * 8) = make_uint2(lo, hi);
}

// ---------------- main GEMM ----------------
__global__ __launch_bounds__(256, 2)
void qlin_gemm(const uint8_t* __restrict__ wsA, const uint8_t* __restrict__ wsB,
               const float* __restrict__ sc, const float* __restrict__ bias,
               float* __restrict__ y)
{
    __shared__ __align__(16) uint8_t ldsA[2][BM * 64];   // 2 x 16KB, linear (glds dest), swizzled at source
    __shared__ __align__(16) uint8_t ldsB[2][64 * 128];  // 2 x 8KB: row np, 16 x 8B granules

    const int tid  = threadIdx.x;
    const int lane = tid & 63;
    const int wid  = tid >> 6;          // 0..3
    const int wr = wid >> 1, wc = wid & 1;   // wave tile 128x64

    // bijective XCD swizzle: 1376 = 8 * 172
    const int lb = (blockIdx.x & 7) * 172 + (blockIdx.x >> 3);
    const int mt = lb / NTN, nt = lb % NTN;
    const int m0 = mt * BM, n0 = nt * BN;

    const int cl = lane & 15;
    const int k8 = lane >> 4;           // 0..3

    // ---- A fragment offsets (constant) ----
    int aOff[8];
#pragma unroll
    for (int i = 0; i < 8; ++i) {
        int ml = wr * 128 + i * 16 + cl;
        aOff[i] = ml * 64 + ((k8 * 16) ^ swzA(ml));
    }
    // ---- B fragment offsets: 2 x b64 per frag ----
    int bOff[4][2];
#pragma unroll
    for (int j = 0; j < 4; ++j) {
        int n = wc * 64 + j * 16 + cl;
        int npr = n >> 1, p = n & 1;
#pragma unroll
        for (int h = 0; h < 2; ++h) {
            int q8 = k8 * 2 + h;
            bOff[j][h] = npr * 128 + (((q8 ^ (npr & 7)) << 4)) + (((p ^ ((npr >> 3) & 1)) << 3));
        }
    }
    // ---- B writer role: np = tid&63, koct = wid ----
    const int npw  = tid & 63;
    const int koct = wid;
    const int sww  = (npw >> 3) & 1;
    int wOff[2][2];   // [kq][p]
#pragma unroll
    for (int kq = 0; kq < 2; ++kq)
#pragma unroll
        for (int p = 0; p < 2; ++p)
            wOff[kq][p] = npw * 128 + ((((koct * 2 + kq) ^ (npw & 7)) << 4)) + (((p ^ sww) << 3));

    const size_t npg = (size_t)(n0 >> 1) + npw;          // global np column
    const uint8_t* wsAbase = wsA + (size_t)mt * NSTEP * ACHUNK;
    const float* scb = sc + n0 + 2 * npw;

    f32x4 acc[8][4];
#pragma unroll
    for (int i = 0; i < 8; ++i)
#pragma unroll
        for (int j = 0; j < 4; ++j)
            acc[i][j] = (f32x4){0.f, 0.f, 0.f, 0.f};

    auto issueA = [&](int t, int buf) {
        const uint8_t* g = wsAbase + (size_t)t * ACHUNK + tid * 16;
        lds_u8_t* l = (lds_u8_t*)(&ldsA[buf][tid * 16]);
#pragma unroll
        for (int q = 0; q < 4; ++q)
            __builtin_amdgcn_global_load_lds((glb_u8_t*)(g + q * 4096), l + q * 4096, 16, 0, 0);
    };
    auto loadB = [&](int t) {
        return *reinterpret_cast<const uint2*>(wsB + ((size_t)(t * 4 + koct) * PLD + npg) * 8);
    };
    auto loadS = [&](int t) {
        return *reinterpret_cast<const float2*>(scb + (size_t)(t >> 2) * NOUT);
    };
    auto decodeWrite = [&](uint2 braw, float2 s, int buf) {
        uint8_t* Lb = ldsB[buf];
        const float a0 = -8.f * s.x, a1 = -8.f * s.y;
        uint32_t l0 = braw.x & 0x0F0F0F0Fu, h0 = (braw.x >> 4) & 0x0F0F0F0Fu;
        uint32_t l1 = braw.y & 0x0F0F0F0Fu, h1 = (braw.y >> 4) & 0x0F0F0F0Fu;
        float fe[8], fo[8];
#pragma unroll
        for (int i = 0; i < 4; ++i) {
            fe[i]     = fmaf((float)((l0 >> (8 * i)) & 0xFFu), s.x, a0);
            fe[i + 4] = fmaf((float)((l1 >> (8 * i)) & 0xFFu), s.x, a0);
            fo[i]     = fmaf((float)((h0 >> (8 * i)) & 0xFFu), s.y, a1);
            fo[i + 4] = fmaf((float)((h1 >> (8 * i)) & 0xFFu), s.y, a1);
        }
        // granule (kq, p): 4 bf16 of k = koct*8 + kq*4 + 0..3
        uint2 g;
        g.x = bfpack(fe[0], fe[1]); g.y = bfpack(fe[2], fe[3]);
        *reinterpret_cast<uint2*>(Lb + wOff[0][0]) = g;
        g.x = bfpack(fe[4], fe[5]); g.y = bfpack(fe[6], fe[7]);
        *reinterpret_cast<uint2*>(Lb + wOff[1][0]) = g;
        g.x = bfpack(fo[0], fo[1]); g.y = bfpack(fo[2], fo[3]);
        *reinterpret_cast<uint2*>(Lb + wOff[0][1]) = g;
        g.x = bfpack(fo[4], fo[5]); g.y = bfpack(fo[6], fo[7]);
        *reinterpret_cast<uint2*>(Lb + wOff[1][1]) = g;
    };
    auto compute = [&](int buf) {
        const uint8_t* La = ldsA[buf];
        const uint8_t* Lb = ldsB[buf];
        bf16x8 af[8], bfr[4];
#pragma unroll
        for (int i = 0; i < 8; ++i)
            af[i] = *reinterpret_cast<const bf16x8*>(La + aOff[i]);
#pragma unroll
        for (int j = 0; j < 4; ++j) {
            uint64_t v[2];
            v[0] = *reinterpret_cast<const uint64_t*>(Lb + bOff[j][0]);
            v[1] = *reinterpret_cast<const uint64_t*>(Lb + bOff[j][1]);
            __builtin_memcpy(&bfr[j], v, 16);
        }
#pragma unroll
        for (int i = 0; i < 8; ++i)
#pragma unroll
            for (int j = 0; j < 4; ++j)
                acc[i][j] = __builtin_amdgcn_mfma_f32_16x16x32_bf16(af[i], bfr[j], acc[i][j], 0, 0, 0);
    };

    // prologue: stage tile 0
    issueA(0, 0);
    {
        uint2 b0 = loadB(0);
        float2 s0 = loadS(0);
        decodeWrite(b0, s0, 0);
    }
    __syncthreads();

    int cur = 0;
#pragma unroll 1
    for (int t = 0; t < NSTEP; ++t) {
        const int nxt = cur ^ 1;
        uint2 braw; float2 sfl;
        if (t + 1 < NSTEP) {
            issueA(t + 1, nxt);          // async global->LDS, drained by barrier
            braw = loadB(t + 1);         // global->reg, consumed after compute
            sfl  = loadS(t + 1);
        }
        compute(cur);
        if (t + 1 < NSTEP) decodeWrite(braw, sfl, nxt);
        __syncthreads();
        cur = nxt;
    }

    // ---- epilogue ----
    float bv[4];
#pragma unroll
    for (int j = 0; j < 4; ++j) bv[j] = bias[n0 + wc * 64 + j * 16 + cl];
    const int rg = (lane >> 4) * 4;
#pragma unroll
    for (int i = 0; i < 8; ++i) {
        const int mrow = m0 + wr * 128 + i * 16 + rg;
#pragma unroll
        for (int r = 0; r < 4; ++r) {
            float* yp = y + (size_t)(mrow + r) * NOUT + n0 + wc * 64 + cl;
#pragma unroll
            for (int j = 0; j < 4; ++j)
                yp[j * 16] = acc[i][j][r] + bv[j];
        }
    }
}

extern "C" void kernel_launch(void* const* d_in, const int* in_sizes, int n_in,
                              void* d_out, int out_size, void* d_ws, size_t ws_size,
                              hipStream_t stream)
{
    const float*   xin  = (const float*)d_in[0];
    const int32_t* pw   = (const int32_t*)d_in[1];   // harness pushes int8 as int32
    const float*   scal = (const float*)d_in[2];
    const float*   bias = (const float*)d_in[3];
    float* y = (float*)d_out;

    uint8_t* wsA = (uint8_t*)d_ws;
    uint8_t* wsB = wsA + WSB_OFF;

    prepA<<<dim3((MTOK * (KIN / 4)) / 256), 256, 0, stream>>>(xin, wsA);
    prepB<<<dim3(43, 512), 128, 0, stream>>>(pw, wsB);
    qlin_gemm<<<dim3(NTM * NTN), 256, 0, stream>>>(wsA, wsB, scal, bias, y);
}

// Round 5
// 452.595 us; speedup vs baseline: 1.6334x; 1.1394x over previous
//
#include <hip/hip_runtime.h>
#include <hip/hip_bf16.h>
#include <stdint.h>

#define NOUT 11008
#define KIN  4096
#define MTOK 4096
#define PLD  5504            // int32 elements per k-row of pw
#define BM 256
#define BN 128
#define BK 32
#define NSTEP (KIN/BK)       // 128
#define NTN (NOUT/BN)        // 86
#define NTM (MTOK/BM)        // 16
#define ACHUNK 16384         // bytes per (mt,t) A chunk: 256 rows * 64B
#define WSA_BYTES ((size_t)NTM * NSTEP * ACHUNK)        // 32 MB
#define WSB_OFF   WSA_BYTES

typedef short bf16x8 __attribute__((ext_vector_type(8)));
typedef float f32x4  __attribute__((ext_vector_type(4)));

typedef __attribute__((address_space(3))) uint8_t lds_u8_t;
typedef __attribute__((address_space(1))) const uint8_t glb_u8_t;

__device__ __forceinline__ uint32_t bfpack(float lo, float hi){
    __hip_bfloat16 a = __float2bfloat16(lo);
    __hip_bfloat16 b = __float2bfloat16(hi);
    uint16_t ua, ub;
    __builtin_memcpy(&ua, &a, 2);
    __builtin_memcpy(&ub, &b, 2);
    return (uint32_t)ua | ((uint32_t)ub << 16);
}

// A-LDS swizzle: rows are 64B (32k * 2B)
__device__ __forceinline__ int swzA(int m){ return ((m >> 1) & 3) << 4; }

// ---------------- pre-pass A: x fp32 -> bf16, tiled+swizzled into wsA ----------------
__global__ __launch_bounds__(256)
void prepA(const float* __restrict__ x, uint8_t* __restrict__ wsA)
{
    int gid = blockIdx.x * 256 + threadIdx.x;      // 4096 * 1024
    int m  = gid >> 10;
    int k  = (gid & 1023) << 2;
    float4 v = *reinterpret_cast<const float4*>(x + (size_t)m * KIN + k);
    uint32_t lo = bfpack(v.x, v.y), hi = bfpack(v.z, v.w);
    int mt = m >> 8, ml = m & 255, t = k >> 5, kl = k & 31;
    size_t dst = (size_t)(mt * NSTEP + t) * ACHUNK + ml * 64 + ((kl * 2) ^ swzA(ml));
    *reinterpret_cast<uint2*>(wsA + dst) = make_uint2(lo, hi);
}

// ---------------- pre-pass B: int32-inflated nibble-pairs -> compact bytes, k-transposed ----------------
// wsB layout: [koct 0..511][np 0..5503] of 8B: bytes for k = koct*8+0..7 at column np.
__global__ __launch_bounds__(128)
void prepB(const int32_t* __restrict__ pw, uint8_t* __restrict__ wsB)
{
    int np   = blockIdx.x * 128 + threadIdx.x;     // 43*128 = 5504
    int koct = blockIdx.y;                         // 0..511
    const int32_t* p = pw + (size_t)koct * 8 * PLD + np;
    uint32_t b[8];
#pragma unroll
    for (int i = 0; i < 8; ++i) b[i] = (uint32_t)p[(size_t)i * PLD] & 0xFFu;
    uint32_t lo = b[0] | (b[1] << 8) | (b[2] << 16) | (b[3] << 24);
    uint32_t hi = b[4] | (b[5] << 8) | (b[6] << 16) | (b[7] << 24);
    *reinterpret_cast<uint2*>(wsB + ((size_t)koct * PLD + np) * 8) = make_uint2(lo, hi);
}

// ---------------- main GEMM ----------------
__global__ __launch_bounds__(256, 2)
void qlin_gemm(const uint8_t* __restrict__ wsA, const uint8_t* __restrict__ wsB,
               const float* __restrict__ sc, const float* __restrict__ bias,
               float* __restrict__ y)
{
    __shared__ __align__(16) uint8_t ldsA[3][BM * 64];   // 3 x 16KB, linear dest (glds), swizzled source
    __shared__ __align__(16) uint8_t ldsB[3][64 * 128];  // 3 x 8KB

    const int tid  = threadIdx.x;
    const int lane = tid & 63;
    const int wid  = tid >> 6;          // 0..3
    const int wr = wid >> 1, wc = wid & 1;   // wave tile 128x64

    // bijective XCD swizzle: 1376 = 8 * 172
    const int lb = (blockIdx.x & 7) * 172 + (blockIdx.x >> 3);
    const int mt = lb / NTN, nt = lb % NTN;
    const int m0 = mt * BM, n0 = nt * BN;

    const int cl = lane & 15;
    const int k8 = lane >> 4;           // 0..3

    // ---- A fragment offsets (constant) ----
    int aOff[8];
#pragma unroll
    for (int i = 0; i < 8; ++i) {
        int ml = wr * 128 + i * 16 + cl;
        aOff[i] = ml * 64 + ((k8 * 16) ^ swzA(ml));
    }
    // ---- B fragment offsets: 2 x b64 per frag ----
    int bOff[4][2];
#pragma unroll
    for (int j = 0; j < 4; ++j) {
        int n = wc * 64 + j * 16 + cl;
        int npr = n >> 1, p = n & 1;
#pragma unroll
        for (int h = 0; h < 2; ++h) {
            int q8 = k8 * 2 + h;
            bOff[j][h] = npr * 128 + (((q8 ^ (npr & 7)) << 4)) + (((p ^ ((npr >> 3) & 1)) << 3));
        }
    }
    // ---- B writer role: np = tid&63, koct = wid ----
    const int npw  = tid & 63;
    const int koct = wid;
    const int sww  = (npw >> 3) & 1;
    int wOff[2][2];   // [kq][p]
#pragma unroll
    for (int kq = 0; kq < 2; ++kq)
#pragma unroll
        for (int p = 0; p < 2; ++p)
            wOff[kq][p] = npw * 128 + ((((koct * 2 + kq) ^ (npw & 7)) << 4)) + (((p ^ sww) << 3));

    const size_t npg = (size_t)(n0 >> 1) + npw;          // global np column
    const uint8_t* wsAbase = wsA + (size_t)mt * NSTEP * ACHUNK;
    const float* scb = sc + n0 + 2 * npw;

    f32x4 acc[8][4];
#pragma unroll
    for (int i = 0; i < 8; ++i)
#pragma unroll
        for (int j = 0; j < 4; ++j)
            acc[i][j] = (f32x4){0.f, 0.f, 0.f, 0.f};

    auto issueA = [&](int t, int buf) {
        const uint8_t* g = wsAbase + (size_t)t * ACHUNK + tid * 16;
        lds_u8_t* l = (lds_u8_t*)(&ldsA[buf][tid * 16]);
#pragma unroll
        for (int q = 0; q < 4; ++q)
            __builtin_amdgcn_global_load_lds((glb_u8_t*)(g + q * 4096), l + q * 4096, 16, 0, 0);
    };
    auto loadB = [&](int t) {
        return *reinterpret_cast<const uint2*>(wsB + ((size_t)(t * 4 + koct) * PLD + npg) * 8);
    };
    auto loadS = [&](int t) {
        return *reinterpret_cast<const float2*>(scb + (size_t)(t >> 2) * NOUT);
    };
    auto decodeWrite = [&](uint2 braw, float2 s, int buf) {
        uint8_t* Lb = ldsB[buf];
        const float a0 = -8.f * s.x, a1 = -8.f * s.y;
        uint32_t l0 = braw.x & 0x0F0F0F0Fu, h0 = (braw.x >> 4) & 0x0F0F0F0Fu;
        uint32_t l1 = braw.y & 0x0F0F0F0Fu, h1 = (braw.y >> 4) & 0x0F0F0F0Fu;
        float fe[8], fo[8];
#pragma unroll
        for (int i = 0; i < 4; ++i) {
            fe[i]     = fmaf((float)((l0 >> (8 * i)) & 0xFFu), s.x, a0);
            fe[i + 4] = fmaf((float)((l1 >> (8 * i)) & 0xFFu), s.x, a0);
            fo[i]     = fmaf((float)((h0 >> (8 * i)) & 0xFFu), s.y, a1);
            fo[i + 4] = fmaf((float)((h1 >> (8 * i)) & 0xFFu), s.y, a1);
        }
        uint2 g;
        g.x = bfpack(fe[0], fe[1]); g.y = bfpack(fe[2], fe[3]);
        *reinterpret_cast<uint2*>(Lb + wOff[0][0]) = g;
        g.x = bfpack(fe[4], fe[5]); g.y = bfpack(fe[6], fe[7]);
        *reinterpret_cast<uint2*>(Lb + wOff[1][0]) = g;
        g.x = bfpack(fo[0], fo[1]); g.y = bfpack(fo[2], fo[3]);
        *reinterpret_cast<uint2*>(Lb + wOff[0][1]) = g;
        g.x = bfpack(fo[4], fo[5]); g.y = bfpack(fo[6], fo[7]);
        *reinterpret_cast<uint2*>(Lb + wOff[1][1]) = g;
    };
    auto compute = [&](int buf) {
        const uint8_t* La = ldsA[buf];
        const uint8_t* Lb = ldsB[buf];
        bf16x8 af[8], bfr[4];
#pragma unroll
        for (int i = 0; i < 8; ++i)
            af[i] = *reinterpret_cast<const bf16x8*>(La + aOff[i]);
#pragma unroll
        for (int j = 0; j < 4; ++j) {
            uint64_t v[2];
            v[0] = *reinterpret_cast<const uint64_t*>(Lb + bOff[j][0]);
            v[1] = *reinterpret_cast<const uint64_t*>(Lb + bOff[j][1]);
            __builtin_memcpy(&bfr[j], v, 16);
        }
        __builtin_amdgcn_s_setprio(1);
#pragma unroll
        for (int i = 0; i < 8; ++i)
#pragma unroll
            for (int j = 0; j < 4; ++j)
                acc[i][j] = __builtin_amdgcn_mfma_f32_16x16x32_bf16(af[i], bfr[j], acc[i][j], 0, 0, 0);
        __builtin_amdgcn_s_setprio(0);
    };

    // ---- prologue: tiles 0 and 1 in flight ----
    issueA(0, 0);
    asm volatile("" ::: "memory");                 // order: glds(0) before bld(0)
    uint2  braw_cur = loadB(0);
    float2 sfl_cur  = loadS(0);
    asm volatile("" ::: "memory");
    issueA(1, 1);
    asm volatile("" ::: "memory");                 // order: glds(1) before bld(1)
    uint2  braw_nxt = loadB(1);
    float2 sfl_nxt  = loadS(1);
    asm volatile("" ::: "memory");
    decodeWrite(braw_cur, sfl_cur, 0);             // auto vmcnt wait on braw_cur drains glds(0)
    asm volatile("s_waitcnt vmcnt(6) lgkmcnt(0)" ::: "memory");
    __builtin_amdgcn_sched_barrier(0);
    __builtin_amdgcn_s_barrier();
    asm volatile("" ::: "memory");

    int bc = 0, bw = 1, bi = 2;
#pragma unroll 1
    for (int t = 0; t < NSTEP; ++t) {
        const int tp = (t + 2 < NSTEP) ? (t + 2) : (NSTEP - 1);  // uniform: every step issues 6 vmem
        issueA(tp, bi);
        asm volatile("" ::: "memory");             // glds before reg-loads (FIFO drain guarantee)
        uint2  braw2 = loadB(tp);
        float2 sfl2  = loadS(tp);
        decodeWrite(braw_nxt, sfl_nxt, bw);        // tile t+1 -> buffer bw
        compute(bc);                               // tile t
        braw_nxt = braw2; sfl_nxt = sfl2;
        // counted drain: leave this step's 6 vmem in flight; everything older done
        asm volatile("s_waitcnt vmcnt(6) lgkmcnt(0)" ::: "memory");
        __builtin_amdgcn_sched_barrier(0);
        __builtin_amdgcn_s_barrier();
        asm volatile("" ::: "memory");
        int nb = bc; bc = bw; bw = bi; bi = nb;
    }

    // ---- epilogue ----
    float bv[4];
#pragma unroll
    for (int j = 0; j < 4; ++j) bv[j] = bias[n0 + wc * 64 + j * 16 + cl];
    const int rg = (lane >> 4) * 4;
#pragma unroll
    for (int i = 0; i < 8; ++i) {
        const int mrow = m0 + wr * 128 + i * 16 + rg;
#pragma unroll
        for (int r = 0; r < 4; ++r) {
            float* yp = y + (size_t)(mrow + r) * NOUT + n0 + wc * 64 + cl;
#pragma unroll
            for (int j = 0; j < 4; ++j)
                yp[j * 16] = acc[i][j][r] + bv[j];
        }
    }
}

extern "C" void kernel_launch(void* const* d_in, const int* in_sizes, int n_in,
                              void* d_out, int out_size, void* d_ws, size_t ws_size,
                              hipStream_t stream)
{
    const float*   xin  = (const float*)d_in[0];
    const int32_t* pw   = (const int32_t*)d_in[1];   // harness pushes int8 as int32
    const float*   scal = (const float*)d_in[2];
    const float*   bias = (const float*)d_in[3];
    float* y = (float*)d_out;

    uint8_t* wsA = (uint8_t*)d_ws;
    uint8_t* wsB = wsA + WSB_OFF;

    prepA<<<dim3((MTOK * (KIN / 4)) / 256), 256, 0, stream>>>(xin, wsA);
    prepB<<<dim3(43, 512), 128, 0, stream>>>(pw, wsB);
    qlin_gemm<<<dim3(NTM * NTN), 256, 0, stream>>>(wsA, wsB, scal, bias, y);
}